// Round 1
// baseline (410.165 us; speedup 1.0000x reference)
//
#include <hip/hip_runtime.h>

#define EPS 1e-8f

using f32x4 = __attribute__((ext_vector_type(4))) float;

// B=4, C=128, H=W=256, HW=65536, mask 128x128 per batch (nearest-upsample 2x2)
// Phase 1: partial moment sums, software-pipelined.
// grid = 512*4 chunks, 256 threads, 8 groups of 8 floats/thread.
// 2048 blocks -> 8 blocks/CU -> 32 waves/CU (VGPR<=64), vs previous 1024 (50% cap).
// stats[(bc*4+chunk)*12 + j]:
//  j: 0 Σx1 m   1 Σx1 m³   2 Σx1² m⁴   3..5 same for x2
//     6 Σx1 om  7 Σx1 om³  8 Σx1² om⁴  9..11 same for x2
__global__ __launch_bounds__(256, 8) void k_stats(
    const float* __restrict__ x1,
    const float* __restrict__ x2,
    const float* __restrict__ mask,
    float* __restrict__ stats)
{
    int blk   = blockIdx.x;        // [0, 2048)
    int chunk = blk & 3;
    int bc    = blk >> 2;          // b*128 + c
    int b     = bc >> 7;
    int tid   = threadIdx.x;

    const size_t poff = (size_t)bc * 65536 + (size_t)chunk * 16384;
    const float* xp1 = x1 + poff;
    const float* xp2 = x2 + poff;
    const float* mp  = mask + b * 16384;
    const int gi0 = chunk * 16384 + tid * 8;   // within-plane index of group 0

    float a[12];
#pragma unroll
    for (int j = 0; j < 12; ++j) a[j] = 0.f;

    // current-group registers (prefetched, 1-deep pipeline)
    int off0 = tid * 8;
    f32x4 c1a = *(const f32x4*)(xp1 + off0);
    f32x4 c1b = *(const f32x4*)(xp1 + off0 + 4);
    f32x4 c2a = *(const f32x4*)(xp2 + off0);
    f32x4 c2b = *(const f32x4*)(xp2 + off0 + 4);
    int h0 = gi0 >> 8, w0 = gi0 & 255;
    f32x4 cm = *(const f32x4*)(mp + (h0 >> 1) * 128 + (w0 >> 1));

    for (int g = 0; g < 8; ++g) {
        f32x4 n1a, n1b, n2a, n2b, nm;
        if (g < 7) {
            int off = (g + 1) * 2048 + tid * 8;
            int gi  = gi0 + (g + 1) * 2048;
            int h = gi >> 8, w = gi & 255;
            n1a = *(const f32x4*)(xp1 + off);
            n1b = *(const f32x4*)(xp1 + off + 4);
            n2a = *(const f32x4*)(xp2 + off);
            n2b = *(const f32x4*)(xp2 + off + 4);
            nm  = *(const f32x4*)(mp + (h >> 1) * 128 + (w >> 1));
        }
#pragma unroll
        for (int j = 0; j < 8; ++j) {
            float m  = cm[j >> 1];
            float om = 1.f - m;
            float m2 = m * m, om2 = om * om;
            float f1 = (j < 4) ? c1a[j & 3] : c1b[j & 3];
            float f2 = (j < 4) ? c2a[j & 3] : c2b[j & 3];
            float p1 = f1 * m2,  p2 = f2 * m2;
            a[0] += f1 * m;  a[1] += p1 * m;  a[2] += p1 * p1;
            a[3] += f2 * m;  a[4] += p2 * m;  a[5] += p2 * p2;
            float q1 = f1 * om2, q2 = f2 * om2;
            a[6] += f1 * om; a[7] += q1 * om; a[8] += q1 * q1;
            a[9] += f2 * om; a[10]+= q2 * om; a[11]+= q2 * q2;
        }
        c1a = n1a; c1b = n1b; c2a = n2a; c2b = n2b; cm = nm;
    }

#pragma unroll
    for (int j = 0; j < 12; ++j)
#pragma unroll
        for (int d = 32; d > 0; d >>= 1)
            a[j] += __shfl_down(a[j], d, 64);

    __shared__ float red[4][12];
    int wv = tid >> 6, ln = tid & 63;
    if (ln == 0) {
#pragma unroll
        for (int j = 0; j < 12; ++j) red[wv][j] = a[j];
    }
    __syncthreads();
    if (tid < 12) {
        float v = red[0][tid] + red[1][tid] + red[2][tid] + red[3][tid];
        stats[(size_t)blk * 12 + tid] = v;
    }
}

// Phase 2: per-batch stats + 4 small matvecs.
// grid = B*4 (one block per (batch, matrix)), 256 threads.
// Mask-sum + per-c stats recomputed redundantly per block (64KB read, trivial);
// removes the 4-CU serialization of the old single-kernel version.
// derived[(b*128+c)*8 + {0..7}] = {mean_in, inv_in, mean_out, inv_out,
//                                  ada_in_mean, ada_in_var, ada_out_mean, ada_out_var}
__global__ __launch_bounds__(256) void k_mod(
    const float* __restrict__ mask,
    const float* __restrict__ w_in_mean,
    const float* __restrict__ w_in_var,
    const float* __restrict__ w_out_mean,
    const float* __restrict__ w_out_var,
    const float* __restrict__ stats,
    float* __restrict__ derived)
{
    int b   = blockIdx.x >> 2;
    int mat = blockIdx.x & 3;
    int tid = threadIdx.x;

    // mask sums over half-res grid (upsampled sums are 4x)
    const float* mp = mask + b * 16384;
    float sm = 0.f, sm2 = 0.f;
    for (int it = 0; it < 16; ++it) {
        const f32x4 mv = *(const f32x4*)(mp + (it * 256 + tid) * 4);
#pragma unroll
        for (int j = 0; j < 4; ++j) { float m = mv[j]; sm += m; sm2 += m * m; }
    }
#pragma unroll
    for (int d = 32; d > 0; d >>= 1) {
        sm  += __shfl_down(sm, d, 64);
        sm2 += __shfl_down(sm2, d, 64);
    }
    __shared__ float rr[8];
    __shared__ float SMs, SM2s;
    int wv = tid >> 6, ln = tid & 63;
    if (ln == 0) { rr[wv] = sm; rr[4 + wv] = sm2; }
    __syncthreads();
    if (tid == 0) {
        SMs  = 4.f * (rr[0] + rr[1] + rr[2] + rr[3]);
        SM2s = 4.f * (rr[4] + rr[5] + rr[6] + rr[7]);
    }
    __syncthreads();
    float SM = SMs, SM2 = SM2s;
    float n_in  = SM + EPS;
    float n_out = 65536.f - SM + EPS;
    float SOM2  = 65536.f - 2.f * SM + SM2;

    __shared__ float vec[256];

    if (tid < 128) {
        int c = tid;
        const float* st = stats + (size_t)(b * 128 + c) * 4 * 12;
        float s[12];
#pragma unroll
        for (int j = 0; j < 12; ++j)
            s[j] = (st[j] + st[12 + j]) + (st[24 + j] + st[36 + j]);
        float mi1 = s[0] / n_in;
        float vi1 = fmaxf((s[2] - 2.f * mi1 * s[1] + mi1 * mi1 * SM2) / n_in, 0.f);
        float mi2 = s[3] / n_in;
        float vi2 = fmaxf((s[5] - 2.f * mi2 * s[4] + mi2 * mi2 * SM2) / n_in, 0.f);
        float mo1 = s[6] / n_out;
        float vo1 = fmaxf((s[8] - 2.f * mo1 * s[7] + mo1 * mo1 * SOM2) / n_out, 0.f);
        float mo2 = s[9] / n_out;
        float vo2 = fmaxf((s[11] - 2.f * mo2 * s[10] + mo2 * mo2 * SOM2) / n_out, 0.f);
        float v0, v1;
        if (mat == 0)      { v0 = mi1; v1 = mi2; }
        else if (mat == 1) { v0 = vi1; v1 = vi2; }
        else if (mat == 2) { v0 = mo1; v1 = mo2; }
        else               { v0 = vo1; v1 = vo2; }
        vec[c] = v0; vec[128 + c] = v1;
        if (mat == 0) {
            float* d = derived + (size_t)(b * 128 + c) * 8;
            d[0] = mi1; d[1] = rsqrtf(vi1 + EPS);
            d[2] = mo1; d[3] = rsqrtf(vo1 + EPS);
        }
    }
    __syncthreads();

    // matvec: 2 lanes per row (halves of length 128), combine via shfl_xor
    const float* wp = (mat == 0) ? w_in_mean :
                      (mat == 1) ? w_in_var :
                      (mat == 2) ? w_out_mean : w_out_var;
    int row = tid >> 1, half = tid & 1;
    const float* wr = wp + row * 256 + half * 128;
    const float* vp = vec + half * 128;
    float acc = 0.f;
    for (int k = 0; k < 128; k += 4) {
        f32x4 w4 = *(const f32x4*)(wr + k);
#pragma unroll
        for (int j = 0; j < 4; ++j) acc += w4[j] * vp[k + j];
    }
    acc += __shfl_xor(acc, 1, 64);
    if (half == 0)
        derived[(size_t)(b * 128 + row) * 8 + 4 + mat] = acc;
}

// Phase 3: elementwise apply, software-pipelined. grid = 512*4, 256 threads,
// 64 els/thread in 8 groups of 8. Already 8 blocks/CU -> 32 waves/CU.
__global__ __launch_bounds__(256, 8) void k_apply(
    const float* __restrict__ x1,
    const float* __restrict__ mask,
    const float* __restrict__ derived,
    float* __restrict__ out)
{
    int blk   = blockIdx.x;        // [0, 2048)
    int bc    = blk >> 2;
    int chunk = blk & 3;
    int b     = bc >> 7;
    const float* d = derived + (size_t)bc * 8;
    float mean_in = d[0], inv_in = d[1], mean_out = d[2], inv_out = d[3];
    float am_in = d[4], av_in = d[5], am_out = d[6], av_out = d[7];
    float ci1 = inv_in * av_in;
    float ci0 = am_in - mean_in * ci1;
    float co1 = inv_out * av_out;
    float co0 = am_out - mean_out * co1;

    int tid = threadIdx.x;
    const float* xp = x1 + (size_t)bc * 65536;
    float* op = out + (size_t)bc * 65536;
    const float* mp = mask + b * 16384;
    const int gi0 = chunk * 16384 + tid * 8;

    f32x4 cxa = *(const f32x4*)(xp + gi0);
    f32x4 cxb = *(const f32x4*)(xp + gi0 + 4);
    int h0 = gi0 >> 8, w0 = gi0 & 255;
    f32x4 cm = *(const f32x4*)(mp + (h0 >> 1) * 128 + (w0 >> 1));

    for (int g = 0; g < 8; ++g) {
        f32x4 nxa, nxb, nm;
        if (g < 7) {
            int gi = gi0 + (g + 1) * 2048;
            int h = gi >> 8, w = gi & 255;
            nxa = *(const f32x4*)(xp + gi);
            nxb = *(const f32x4*)(xp + gi + 4);
            nm  = *(const f32x4*)(mp + (h >> 1) * 128 + (w >> 1));
        }
        f32x4 oa, ob;
#pragma unroll
        for (int j = 0; j < 8; ++j) {
            float m  = cm[j >> 1];
            float om = 1.f - m;
            float x  = (j < 4) ? cxa[j & 3] : cxb[j & 3];
            float r  = x * (m * m * ci1 + om * om * co1) + ci0 * m + co0 * om;
            if (j < 4) oa[j & 3] = r; else ob[j & 3] = r;
        }
        int go = gi0 + g * 2048;
        __builtin_nontemporal_store(oa, (f32x4*)(op + go));
        __builtin_nontemporal_store(ob, (f32x4*)(op + go + 4));
        cxa = nxa; cxb = nxb; cm = nm;
    }
}

extern "C" void kernel_launch(void* const* d_in, const int* in_sizes, int n_in,
                              void* d_out, int out_size, void* d_ws, size_t ws_size,
                              hipStream_t stream) {
    const float* x1        = (const float*)d_in[0];
    const float* x2        = (const float*)d_in[1];
    const float* mask      = (const float*)d_in[2];
    const float* w_in_mean = (const float*)d_in[3];
    const float* w_in_var  = (const float*)d_in[4];
    const float* w_out_mean= (const float*)d_in[5];
    const float* w_out_var = (const float*)d_in[6];

    float* stats   = (float*)d_ws;              // 2048 * 12 floats
    float* derived = stats + 2048 * 12;         // 512 * 8 floats
    float* out = (float*)d_out;

    k_stats<<<512 * 4, 256, 0, stream>>>(x1, x2, mask, stats);
    k_mod<<<4 * 4, 256, 0, stream>>>(mask, w_in_mean, w_in_var, w_out_mean, w_out_var,
                                     stats, derived);
    k_apply<<<512 * 4, 256, 0, stream>>>(x1, mask, derived, out);
}

// Round 3
// 361.505 us; speedup vs baseline: 1.1346x; 1.1346x over previous
//
#include <hip/hip_runtime.h>

#define EPS 1e-8f

using f32x4 = __attribute__((ext_vector_type(4))) float;

// B=4, C=128, H=W=256, HW=65536, mask 128x128 per batch (nearest-upsample 2x2)
// Phase 1: partial moment sums, software-pipelined.
// grid = 512*4 chunks, 256 threads, 8 groups of 8 floats/thread.
// 2048 blocks -> 8 blocks/CU; VGPR ~52 <= 64 so HW allows 8 waves/SIMD naturally.
// NOTE: do NOT add a min-waves __launch_bounds__ hint here — (256,8) forced
// VGPR 52->32 and spilled the pipeline to scratch (WRITE_SIZE 64KB->252MB, +39us).
// stats[(bc*4+chunk)*12 + j]:
//  j: 0 Σx1 m   1 Σx1 m³   2 Σx1² m⁴   3..5 same for x2
//     6 Σx1 om  7 Σx1 om³  8 Σx1² om⁴  9..11 same for x2
__global__ __launch_bounds__(256) void k_stats(
    const float* __restrict__ x1,
    const float* __restrict__ x2,
    const float* __restrict__ mask,
    float* __restrict__ stats)
{
    int blk   = blockIdx.x;        // [0, 2048)
    int chunk = blk & 3;
    int bc    = blk >> 2;          // b*128 + c
    int b     = bc >> 7;
    int tid   = threadIdx.x;

    const size_t poff = (size_t)bc * 65536 + (size_t)chunk * 16384;
    const float* xp1 = x1 + poff;
    const float* xp2 = x2 + poff;
    const float* mp  = mask + b * 16384;
    const int gi0 = chunk * 16384 + tid * 8;   // within-plane index of group 0

    float a[12];
#pragma unroll
    for (int j = 0; j < 12; ++j) a[j] = 0.f;

    // current-group registers (prefetched, 1-deep pipeline)
    int off0 = tid * 8;
    f32x4 c1a = *(const f32x4*)(xp1 + off0);
    f32x4 c1b = *(const f32x4*)(xp1 + off0 + 4);
    f32x4 c2a = *(const f32x4*)(xp2 + off0);
    f32x4 c2b = *(const f32x4*)(xp2 + off0 + 4);
    int h0 = gi0 >> 8, w0 = gi0 & 255;
    f32x4 cm = *(const f32x4*)(mp + (h0 >> 1) * 128 + (w0 >> 1));

    for (int g = 0; g < 8; ++g) {
        f32x4 n1a, n1b, n2a, n2b, nm;
        if (g < 7) {
            int off = (g + 1) * 2048 + tid * 8;
            int gi  = gi0 + (g + 1) * 2048;
            int h = gi >> 8, w = gi & 255;
            n1a = *(const f32x4*)(xp1 + off);
            n1b = *(const f32x4*)(xp1 + off + 4);
            n2a = *(const f32x4*)(xp2 + off);
            n2b = *(const f32x4*)(xp2 + off + 4);
            nm  = *(const f32x4*)(mp + (h >> 1) * 128 + (w >> 1));
        }
#pragma unroll
        for (int j = 0; j < 8; ++j) {
            float m  = cm[j >> 1];
            float om = 1.f - m;
            float m2 = m * m, om2 = om * om;
            float f1 = (j < 4) ? c1a[j & 3] : c1b[j & 3];
            float f2 = (j < 4) ? c2a[j & 3] : c2b[j & 3];
            float p1 = f1 * m2,  p2 = f2 * m2;
            a[0] += f1 * m;  a[1] += p1 * m;  a[2] += p1 * p1;
            a[3] += f2 * m;  a[4] += p2 * m;  a[5] += p2 * p2;
            float q1 = f1 * om2, q2 = f2 * om2;
            a[6] += f1 * om; a[7] += q1 * om; a[8] += q1 * q1;
            a[9] += f2 * om; a[10]+= q2 * om; a[11]+= q2 * q2;
        }
        c1a = n1a; c1b = n1b; c2a = n2a; c2b = n2b; cm = nm;
    }

#pragma unroll
    for (int j = 0; j < 12; ++j)
#pragma unroll
        for (int d = 32; d > 0; d >>= 1)
            a[j] += __shfl_down(a[j], d, 64);

    __shared__ float red[4][12];
    int wv = tid >> 6, ln = tid & 63;
    if (ln == 0) {
#pragma unroll
        for (int j = 0; j < 12; ++j) red[wv][j] = a[j];
    }
    __syncthreads();
    if (tid < 12) {
        float v = red[0][tid] + red[1][tid] + red[2][tid] + red[3][tid];
        stats[(size_t)blk * 12 + tid] = v;
    }
}

// Phase 2: per-batch stats + 4 small matvecs.
// grid = B*4 (one block per (batch, matrix)), 256 threads.
// Mask-sum + per-c stats recomputed redundantly per block (64KB read, trivial);
// removes the 4-CU serialization of the old single-kernel version.
// derived[(b*128+c)*8 + {0..7}] = {mean_in, inv_in, mean_out, inv_out,
//                                  ada_in_mean, ada_in_var, ada_out_mean, ada_out_var}
__global__ __launch_bounds__(256) void k_mod(
    const float* __restrict__ mask,
    const float* __restrict__ w_in_mean,
    const float* __restrict__ w_in_var,
    const float* __restrict__ w_out_mean,
    const float* __restrict__ w_out_var,
    const float* __restrict__ stats,
    float* __restrict__ derived)
{
    int b   = blockIdx.x >> 2;
    int mat = blockIdx.x & 3;
    int tid = threadIdx.x;

    // mask sums over half-res grid (upsampled sums are 4x)
    const float* mp = mask + b * 16384;
    float sm = 0.f, sm2 = 0.f;
    for (int it = 0; it < 16; ++it) {
        const f32x4 mv = *(const f32x4*)(mp + (it * 256 + tid) * 4);
#pragma unroll
        for (int j = 0; j < 4; ++j) { float m = mv[j]; sm += m; sm2 += m * m; }
    }
#pragma unroll
    for (int d = 32; d > 0; d >>= 1) {
        sm  += __shfl_down(sm, d, 64);
        sm2 += __shfl_down(sm2, d, 64);
    }
    __shared__ float rr[8];
    __shared__ float SMs, SM2s;
    int wv = tid >> 6, ln = tid & 63;
    if (ln == 0) { rr[wv] = sm; rr[4 + wv] = sm2; }
    __syncthreads();
    if (tid == 0) {
        SMs  = 4.f * (rr[0] + rr[1] + rr[2] + rr[3]);
        SM2s = 4.f * (rr[4] + rr[5] + rr[6] + rr[7]);
    }
    __syncthreads();
    float SM = SMs, SM2 = SM2s;
    float n_in  = SM + EPS;
    float n_out = 65536.f - SM + EPS;
    float SOM2  = 65536.f - 2.f * SM + SM2;

    __shared__ float vec[256];

    if (tid < 128) {
        int c = tid;
        const float* st = stats + (size_t)(b * 128 + c) * 4 * 12;
        float s[12];
#pragma unroll
        for (int j = 0; j < 12; ++j)
            s[j] = (st[j] + st[12 + j]) + (st[24 + j] + st[36 + j]);
        float mi1 = s[0] / n_in;
        float vi1 = fmaxf((s[2] - 2.f * mi1 * s[1] + mi1 * mi1 * SM2) / n_in, 0.f);
        float mi2 = s[3] / n_in;
        float vi2 = fmaxf((s[5] - 2.f * mi2 * s[4] + mi2 * mi2 * SM2) / n_in, 0.f);
        float mo1 = s[6] / n_out;
        float vo1 = fmaxf((s[8] - 2.f * mo1 * s[7] + mo1 * mo1 * SOM2) / n_out, 0.f);
        float mo2 = s[9] / n_out;
        float vo2 = fmaxf((s[11] - 2.f * mo2 * s[10] + mo2 * mo2 * SOM2) / n_out, 0.f);
        float v0, v1;
        if (mat == 0)      { v0 = mi1; v1 = mi2; }
        else if (mat == 1) { v0 = vi1; v1 = vi2; }
        else if (mat == 2) { v0 = mo1; v1 = mo2; }
        else               { v0 = vo1; v1 = vo2; }
        vec[c] = v0; vec[128 + c] = v1;
        if (mat == 0) {
            float* d = derived + (size_t)(b * 128 + c) * 8;
            d[0] = mi1; d[1] = rsqrtf(vi1 + EPS);
            d[2] = mo1; d[3] = rsqrtf(vo1 + EPS);
        }
    }
    __syncthreads();

    // matvec: 2 lanes per row (halves of length 128), combine via shfl_xor
    const float* wp = (mat == 0) ? w_in_mean :
                      (mat == 1) ? w_in_var :
                      (mat == 2) ? w_out_mean : w_out_var;
    int row = tid >> 1, half = tid & 1;
    const float* wr = wp + row * 256 + half * 128;
    const float* vp = vec + half * 128;
    float acc = 0.f;
    for (int k = 0; k < 128; k += 4) {
        f32x4 w4 = *(const f32x4*)(wr + k);
#pragma unroll
        for (int j = 0; j < 4; ++j) acc += w4[j] * vp[k + j];
    }
    acc += __shfl_xor(acc, 1, 64);
    if (half == 0)
        derived[(size_t)(b * 128 + row) * 8 + 4 + mat] = acc;
}

// Phase 3: elementwise apply, software-pipelined. grid = 512*4, 256 threads,
// 64 els/thread in 8 groups of 8. No min-waves hint (see k_stats note).
__global__ __launch_bounds__(256) void k_apply(
    const float* __restrict__ x1,
    const float* __restrict__ mask,
    const float* __restrict__ derived,
    float* __restrict__ out)
{
    int blk   = blockIdx.x;        // [0, 2048)
    int bc    = blk >> 2;
    int chunk = blk & 3;
    int b     = bc >> 7;
    const float* d = derived + (size_t)bc * 8;
    float mean_in = d[0], inv_in = d[1], mean_out = d[2], inv_out = d[3];
    float am_in = d[4], av_in = d[5], am_out = d[6], av_out = d[7];
    float ci1 = inv_in * av_in;
    float ci0 = am_in - mean_in * ci1;
    float co1 = inv_out * av_out;
    float co0 = am_out - mean_out * co1;

    int tid = threadIdx.x;
    const float* xp = x1 + (size_t)bc * 65536;
    float* op = out + (size_t)bc * 65536;
    const float* mp = mask + b * 16384;
    const int gi0 = chunk * 16384 + tid * 8;

    f32x4 cxa = *(const f32x4*)(xp + gi0);
    f32x4 cxb = *(const f32x4*)(xp + gi0 + 4);
    int h0 = gi0 >> 8, w0 = gi0 & 255;
    f32x4 cm = *(const f32x4*)(mp + (h0 >> 1) * 128 + (w0 >> 1));

    for (int g = 0; g < 8; ++g) {
        f32x4 nxa, nxb, nm;
        if (g < 7) {
            int gi = gi0 + (g + 1) * 2048;
            int h = gi >> 8, w = gi & 255;
            nxa = *(const f32x4*)(xp + gi);
            nxb = *(const f32x4*)(xp + gi + 4);
            nm  = *(const f32x4*)(mp + (h >> 1) * 128 + (w >> 1));
        }
        f32x4 oa, ob;
#pragma unroll
        for (int j = 0; j < 8; ++j) {
            float m  = cm[j >> 1];
            float om = 1.f - m;
            float x  = (j < 4) ? cxa[j & 3] : cxb[j & 3];
            float r  = x * (m * m * ci1 + om * om * co1) + ci0 * m + co0 * om;
            if (j < 4) oa[j & 3] = r; else ob[j & 3] = r;
        }
        int go = gi0 + g * 2048;
        __builtin_nontemporal_store(oa, (f32x4*)(op + go));
        __builtin_nontemporal_store(ob, (f32x4*)(op + go + 4));
        cxa = nxa; cxb = nxb; cm = nm;
    }
}

extern "C" void kernel_launch(void* const* d_in, const int* in_sizes, int n_in,
                              void* d_out, int out_size, void* d_ws, size_t ws_size,
                              hipStream_t stream) {
    const float* x1        = (const float*)d_in[0];
    const float* x2        = (const float*)d_in[1];
    const float* mask      = (const float*)d_in[2];
    const float* w_in_mean = (const float*)d_in[3];
    const float* w_in_var  = (const float*)d_in[4];
    const float* w_out_mean= (const float*)d_in[5];
    const float* w_out_var = (const float*)d_in[6];

    float* stats   = (float*)d_ws;              // 2048 * 12 floats
    float* derived = stats + 2048 * 12;         // 512 * 8 floats
    float* out = (float*)d_out;

    k_stats<<<512 * 4, 256, 0, stream>>>(x1, x2, mask, stats);
    k_mod<<<4 * 4, 256, 0, stream>>>(mask, w_in_mean, w_in_var, w_out_mean, w_out_var,
                                     stats, derived);
    k_apply<<<512 * 4, 256, 0, stream>>>(x1, mask, derived, out);
}